// Round 1
// baseline (3925.232 us; speedup 1.0000x reference)
//
#include <hip/hip_runtime.h>
#include <hip/hip_bf16.h>

// Conv2d 3x3, stride 1, pad 1: x (32,128,56,56) f32 NCHW, w (256,128,3,3) OIHW,
// bias (256,), out (32,256,56,56) f32.
// Round 0: correct fp32 direct conv, register-blocked 8 oC/thread, with
// weights repacked to [k][oc] in d_ws for vectorized (float4) weight loads.

#define CONV_B   32
#define CONV_IC  128
#define CONV_H   56
#define CONV_W   56
#define CONV_OC  256
#define CONV_K   (CONV_IC * 9)   // 1152

// ---------------- weight repack: OIHW -> [k = ic*9+kh*3+kw][oc] ----------------
__global__ void repack_w_kernel(const float* __restrict__ w, float* __restrict__ wr) {
    int idx = blockIdx.x * 256 + threadIdx.x;       // 0 .. OC*K-1
    if (idx >= CONV_OC * CONV_K) return;
    int oc = idx & (CONV_OC - 1);                   // contiguous across lanes -> coalesced store
    int k  = idx >> 8;                              // ic*9 + kh*3 + kw
    wr[idx] = w[(size_t)oc * CONV_K + k];
}

// ---------------- main direct conv ----------------
// grid: (8 oc-blocks, 56 oh, 32 n), block: 256 = 64 ow-lanes x 4 oc-groups.
// Each thread: 1 output pixel, 8 consecutive oC.
template <bool REPACKED>
__global__ __launch_bounds__(256)
void conv3x3_kernel(const float* __restrict__ x,
                    const float* __restrict__ w,      // repacked [k][oc] if REPACKED, else OIHW
                    const float* __restrict__ bias,
                    float* __restrict__ out) {
    const int ow  = threadIdx.x & 63;
    const int ocg = threadIdx.x >> 6;
    const int oh  = blockIdx.y;
    const int n   = blockIdx.z;
    if (ow >= CONV_W) return;

    const int oc0 = blockIdx.x * 32 + ocg * 8;

    float acc[8];
#pragma unroll
    for (int j = 0; j < 8; ++j) acc[j] = 0.f;

    const float* xn = x + (size_t)n * CONV_IC * CONV_H * CONV_W;

    for (int ic = 0; ic < CONV_IC; ++ic) {
        const float* xc = xn + (size_t)ic * CONV_H * CONV_W;
#pragma unroll
        for (int kh = 0; kh < 3; ++kh) {
            const int ih = oh + kh - 1;
            if ((unsigned)ih >= (unsigned)CONV_H) continue;
            const float* xr = xc + ih * CONV_W;
            // halo-safe neighborhood (pad=1 -> zeros outside)
            const float xm = (ow > 0)          ? xr[ow - 1] : 0.f;
            const float x0 =                     xr[ow];
            const float xp = (ow < CONV_W - 1) ? xr[ow + 1] : 0.f;

            if (REPACKED) {
                const float* wp = w + (size_t)((ic * 3 + kh) * 3) * CONV_OC + oc0;
#pragma unroll
                for (int kw = 0; kw < 3; ++kw) {
                    const float xv = (kw == 0) ? xm : ((kw == 1) ? x0 : xp);
                    const float4 w0 = *(const float4*)(wp + kw * CONV_OC);
                    const float4 w1 = *(const float4*)(wp + kw * CONV_OC + 4);
                    acc[0] = fmaf(w0.x, xv, acc[0]);
                    acc[1] = fmaf(w0.y, xv, acc[1]);
                    acc[2] = fmaf(w0.z, xv, acc[2]);
                    acc[3] = fmaf(w0.w, xv, acc[3]);
                    acc[4] = fmaf(w1.x, xv, acc[4]);
                    acc[5] = fmaf(w1.y, xv, acc[5]);
                    acc[6] = fmaf(w1.z, xv, acc[6]);
                    acc[7] = fmaf(w1.w, xv, acc[7]);
                }
            } else {
#pragma unroll
                for (int j = 0; j < 8; ++j) {
                    const float* wj = w + (size_t)(oc0 + j) * CONV_K + ic * 9 + kh * 3;
                    acc[j] = fmaf(wj[0], xm, acc[j]);
                    acc[j] = fmaf(wj[1], x0, acc[j]);
                    acc[j] = fmaf(wj[2], xp, acc[j]);
                }
            }
        }
    }

    const size_t obase = (((size_t)n * CONV_OC + oc0) * CONV_H + oh) * CONV_W + ow;
#pragma unroll
    for (int j = 0; j < 8; ++j) {
        out[obase + (size_t)j * CONV_H * CONV_W] = acc[j] + bias[oc0 + j];
    }
}

extern "C" void kernel_launch(void* const* d_in, const int* in_sizes, int n_in,
                              void* d_out, int out_size, void* d_ws, size_t ws_size,
                              hipStream_t stream) {
    const float* x    = (const float*)d_in[0];
    const float* w    = (const float*)d_in[1];
    const float* bias = (const float*)d_in[2];
    float* out        = (float*)d_out;

    const size_t repack_bytes = (size_t)CONV_OC * CONV_K * sizeof(float); // 1.18 MB
    const bool use_repack = (ws_size >= repack_bytes);

    dim3 grid(CONV_OC / 32, CONV_H, CONV_B);
    dim3 block(256);

    if (use_repack) {
        float* wr = (float*)d_ws;
        const int total = CONV_OC * CONV_K;
        repack_w_kernel<<<(total + 255) / 256, 256, 0, stream>>>(w, wr);
        conv3x3_kernel<true><<<grid, block, 0, stream>>>(x, wr, bias, out);
    } else {
        conv3x3_kernel<false><<<grid, block, 0, stream>>>(x, w, bias, out);
    }
}

// Round 2
// 153.120 us; speedup vs baseline: 25.6351x; 25.6351x over previous
//
#include <hip/hip_runtime.h>
#include <hip/hip_bf16.h>
#include <stdint.h>

// Conv2d 3x3 s1 p1: x (32,128,56,56) f32, w (256,128,3,3) f32, bias (256,), out (32,256,56,56) f32.
// bf16 MFMA implicit GEMM: C[oc][q] = sum_k Wt[k][oc] * Bvirt[k][q], K = 128*9 = 1152.
// Bvirt[k][q] = xp[plane(n,ic)][q + kh*64 + kw]  (xp = zero-padded bf16 copy of x, rows 58, cols 64)

#define CB    32
#define CIC   128
#define CH    56
#define CW    56
#define COC   256
#define CK    1152
#define PLANES (CB*CIC)       // 4096
#define PH    58
#define PW    64
#define PLANE_SZ (PH*PW)      // 3712
#define QV    (CH*PW)         // 3584 virtual cols per image
#define KB_STEPS (CK/64)      // 18
#define WT_SLAB (COC*64)      // 16384 elems per K-step slab

typedef short     bf16x8  __attribute__((ext_vector_type(8)));
typedef float     f32x4   __attribute__((ext_vector_type(4)));
typedef unsigned short u16x8 __attribute__((ext_vector_type(8)));

// ---------------- pad + bf16 cast: x -> xp[4096][58][64] (+512 tail zeros) ----------------
__global__ __launch_bounds__(256)
void pad_x_kernel(const float* __restrict__ x, ushort* __restrict__ xp, int total4) {
    int t = blockIdx.x * 256 + threadIdx.x;
    if (t >= total4) return;
    int i4 = t * 4;
    int plane = i4 / PLANE_SZ;
    int rem   = i4 - plane * PLANE_SZ;
    int r = rem / PW;
    int c0 = rem - r * PW;
    ushort4 v;
    ushort* pv = (ushort*)&v;
#pragma unroll
    for (int j = 0; j < 4; ++j) {
        int c = c0 + j;
        float val = 0.f;
        if (plane < PLANES && r >= 1 && r <= CH && c >= 1 && c <= CW) {
            val = x[((size_t)plane * CH + (r - 1)) * CW + (c - 1)];
        }
        __hip_bfloat16 b = __float2bfloat16(val);
        pv[j] = *(ushort*)&b;
    }
    *(ushort4*)(xp + i4) = v;
}

// ---------------- weight repack: OIHW f32 -> Wt[kb][oc][64] bf16 with baked XOR swizzle ----------------
__global__ __launch_bounds__(256)
void repack_wt_kernel(const float* __restrict__ w, ushort* __restrict__ wt) {
    int t = blockIdx.x * 256 + threadIdx.x;
    if (t >= COC * CK) return;
    int oc = t / CK;
    int k  = t - oc * CK;
    int kb = k >> 6, kl = k & 63;
    int pos = kb * WT_SLAB + (((oc << 6) + kl) ^ ((oc & 7) << 3));  // element-XOR = byte^((oc&7)<<4)
    __hip_bfloat16 b = __float2bfloat16(w[t]);
    wt[pos] = *(ushort*)&b;
}

// ---------------- async global->LDS helper ----------------
__device__ __forceinline__ void gload_lds16(const void* g, void* l) {
    __builtin_amdgcn_global_load_lds(
        (const __attribute__((address_space(1))) uint32_t*)g,
        (__attribute__((address_space(3))) uint32_t*)l, 16, 0, 0);
}

// ---------------- MFMA implicit-GEMM conv ----------------
// grid (896, 2): bx -> (n = bx/28, q0 = (bx%28)*128), by -> oc0 = by*128.
// block 256 = 4 waves, wave tile 64(oc) x 64(q), frags 4x4 of 16x16x32.
__global__ __launch_bounds__(256, 2)
void conv_mfma_kernel(const ushort* __restrict__ wt, const ushort* __restrict__ xp,
                      const float* __restrict__ bias, float* __restrict__ out) {
    __shared__ ushort ldsA[128 * 64];   // [oc_l][k] swizzled: byte ^ ((oc_l&7)<<4)
    __shared__ ushort ldsB[128 * 64];   // [q_l][k]  swizzled: byte ^ (((q_l>>2)&7)<<4)

    const int tid  = threadIdx.x;
    const int lane = tid & 63;
    const int wid  = tid >> 6;
    const int wm   = wid >> 1, wn = wid & 1;
    const int n_img = blockIdx.x / 28;
    const int q0    = (blockIdx.x % 28) * 128;
    const int oc0   = blockIdx.y * 128;

    const int qq = tid & 31;   // B-stage: q_local = 4*qq + i
    const int ko = tid >> 5;   // B-stage: k-octet (k_local = ko*8 + r)

    f32x4 acc[4][4];
#pragma unroll
    for (int m = 0; m < 4; ++m)
#pragma unroll
        for (int n = 0; n < 4; ++n)
#pragma unroll
            for (int e = 0; e < 4; ++e) acc[m][n][e] = 0.f;

    const size_t plane_base = (size_t)n_img * CIC * PLANE_SZ;

    for (int kb = 0; kb < KB_STEPS; ++kb) {
        // ---- B global loads (issued before barrier -> overlap prev MFMA) ----
        uint32_t bq[8][2];
#pragma unroll
        for (int r = 0; r < 8; ++r) {
            int k  = kb * 64 + ko * 8 + r;
            int ic = k / 9;
            int t9 = k - ic * 9;
            int kh = t9 / 3;
            int kw = t9 - kh * 3;
            size_t e = plane_base + (size_t)ic * PLANE_SZ + kh * PW + kw + q0 + 4 * qq;
            size_t a0 = e & ~(size_t)3;           // 4-elem (8B) aligned
            int s = (int)(e & 3);                 // == kw, in {0,1,2}
            uint2 d01 = *(const uint2*)(xp + a0);
            uint32_t d2 = *(const uint32_t*)(xp + a0 + 4);
            uint64_t v01 = ((uint64_t)d01.y << 32) | d01.x;
            uint64_t v12 = ((uint64_t)d2    << 32) | d01.y;
            bq[r][0] = (uint32_t)(v01 >> (16 * s));
            bq[r][1] = (uint32_t)(v12 >> (16 * s));
        }

        __syncthreads();   // previous iteration's frag reads done

        // ---- A stage: global_load_lds, 16 KB linear (swizzle pre-baked in Wt) ----
        {
            const char* src = (const char*)(wt + (size_t)kb * WT_SLAB + oc0 * 64);
            char* dstbase = (char*)ldsA;
#pragma unroll
            for (int c = 0; c < 4; ++c) {
                int chunk = (wid * 4 + c) * 1024;
                gload_lds16(src + chunk + lane * 16, dstbase + chunk);
            }
        }

        // ---- B stage: register transpose -> ds_write_b128 ----
#pragma unroll
        for (int i = 0; i < 4; ++i) {
            int q = 4 * qq + i;
            u16x8 v;
#pragma unroll
            for (int r = 0; r < 8; ++r) {
                uint32_t srcw = (i < 2) ? bq[r][0] : bq[r][1];
                v[r] = (unsigned short)(srcw >> (16 * (i & 1)));
            }
            uint32_t bo = (uint32_t)(q * 128 + ko * 16) ^ (uint32_t)(((q >> 2) & 7) << 4);
            *(u16x8*)((char*)ldsB + bo) = v;
        }

        __syncthreads();   // implies s_waitcnt vmcnt(0) lgkmcnt(0)

        // ---- MFMA: 2 k-halves x 16 mfma ----
#pragma unroll
        for (int kk = 0; kk < 2; ++kk) {
            bf16x8 af[4], bfr[4];
#pragma unroll
            for (int m = 0; m < 4; ++m) {
                int oc_l = wm * 64 + m * 16 + (lane & 15);
                uint32_t bo = (uint32_t)(oc_l * 128 + kk * 64 + (lane >> 4) * 16)
                              ^ (uint32_t)((oc_l & 7) << 4);
                af[m] = *(const bf16x8*)((const char*)ldsA + bo);
            }
#pragma unroll
            for (int n = 0; n < 4; ++n) {
                int q_l = wn * 64 + n * 16 + (lane & 15);
                uint32_t bo = (uint32_t)(q_l * 128 + kk * 64 + (lane >> 4) * 16)
                              ^ (uint32_t)(((q_l >> 2) & 7) << 4);
                bfr[n] = *(const bf16x8*)((const char*)ldsB + bo);
            }
#pragma unroll
            for (int m = 0; m < 4; ++m)
#pragma unroll
                for (int n = 0; n < 4; ++n)
                    acc[m][n] = __builtin_amdgcn_mfma_f32_16x16x32_bf16(af[m], bfr[n], acc[m][n], 0, 0, 0);
        }
    }

    // ---- epilogue: bias + store (discard w >= 56) ----
#pragma unroll
    for (int m = 0; m < 4; ++m) {
        float bv[4];
        int oc_b = oc0 + wm * 64 + m * 16 + (lane >> 4) * 4;
#pragma unroll
        for (int r = 0; r < 4; ++r) bv[r] = bias[oc_b + r];
#pragma unroll
        for (int n = 0; n < 4; ++n) {
            int q_virt = q0 + wn * 64 + n * 16 + (lane & 15);
            int wcol = q_virt & 63;
            if (wcol >= CW) continue;
            int h = q_virt >> 6;
#pragma unroll
            for (int r = 0; r < 4; ++r) {
                int oc = oc_b + r;
                out[(((size_t)n_img * COC + oc) * CH + h) * CW + wcol] = acc[m][n][r] + bv[r];
            }
        }
    }
}

// ---------------- fp32 direct fallback (no workspace needed) ----------------
__global__ __launch_bounds__(256)
void conv3x3_fallback(const float* __restrict__ x, const float* __restrict__ w,
                      const float* __restrict__ bias, float* __restrict__ out) {
    const int ow  = threadIdx.x & 63;
    const int ocg = threadIdx.x >> 6;
    const int oh  = blockIdx.y;
    const int n   = blockIdx.z;
    if (ow >= CW) return;
    const int oc0 = blockIdx.x * 32 + ocg * 8;
    float acc[8];
#pragma unroll
    for (int j = 0; j < 8; ++j) acc[j] = 0.f;
    const float* xn = x + (size_t)n * CIC * CH * CW;
    for (int ic = 0; ic < CIC; ++ic) {
        const float* xc = xn + (size_t)ic * CH * CW;
#pragma unroll
        for (int kh = 0; kh < 3; ++kh) {
            const int ih = oh + kh - 1;
            if ((unsigned)ih >= (unsigned)CH) continue;
            const float* xr = xc + ih * CW;
            const float xm = (ow > 0)      ? xr[ow - 1] : 0.f;
            const float x0 =                 xr[ow];
            const float xp_ = (ow < CW - 1) ? xr[ow + 1] : 0.f;
#pragma unroll
            for (int j = 0; j < 8; ++j) {
                const float* wj = w + (size_t)(oc0 + j) * CK + ic * 9 + kh * 3;
                acc[j] = fmaf(wj[0], xm, acc[j]);
                acc[j] = fmaf(wj[1], x0, acc[j]);
                acc[j] = fmaf(wj[2], xp_, acc[j]);
            }
        }
    }
    const size_t obase = (((size_t)n * COC + oc0) * CH + oh) * CW + ow;
#pragma unroll
    for (int j = 0; j < 8; ++j)
        out[obase + (size_t)j * CH * CW] = acc[j] + bias[oc0 + j];
}

extern "C" void kernel_launch(void* const* d_in, const int* in_sizes, int n_in,
                              void* d_out, int out_size, void* d_ws, size_t ws_size,
                              hipStream_t stream) {
    const float* x    = (const float*)d_in[0];
    const float* w    = (const float*)d_in[1];
    const float* bias = (const float*)d_in[2];
    float* out        = (float*)d_out;

    const size_t wt_bytes  = (size_t)KB_STEPS * WT_SLAB * sizeof(ushort);   // 589,824
    const size_t xp_off    = 1u << 20;                                      // 1 MB aligned
    const int    xp_elems  = PLANES * PLANE_SZ + 512;                       // incl. OOB tail pad
    const size_t need      = xp_off + (size_t)xp_elems * sizeof(ushort);    // ~31.5 MB

    if (ws_size < need) {
        dim3 grid(COC / 32, CH, CB);
        conv3x3_fallback<<<grid, 256, 0, stream>>>(x, w, bias, out);
        return;
    }

    ushort* wt = (ushort*)d_ws;
    ushort* xp = (ushort*)((char*)d_ws + xp_off);

    const int total4 = xp_elems / 4;
    pad_x_kernel<<<(total4 + 255) / 256, 256, 0, stream>>>(x, xp, total4);
    repack_wt_kernel<<<(COC * CK + 255) / 256, 256, 0, stream>>>(w, wt);

    dim3 grid(28 * CB, 2);
    conv_mfma_kernel<<<grid, 256, 0, stream>>>(wt, xp, bias, out);
}